// Round 12
// baseline (211.742 us; speedup 1.0000x reference)
//
#include <hip/hip_runtime.h>

#define M_ROWS 12608          // 64*197
#define K_DIM  768
// Xc: 64 panels x 24 kt x 16 chunks x 512 shorts (chunk = [lane64][k8]) = 25.2 MB
#define XC_ELEMS (64*24*16*512)
// Wc: 12 heads x 24 kt x 12 chunks x 512 shorts = 3.5 MB
#define WC_ELEMS (12*24*12*512)

typedef __bf16 bf16x8 __attribute__((ext_vector_type(8)));
typedef float  f32x4  __attribute__((ext_vector_type(4)));

__device__ __forceinline__ unsigned short f2bf(float f) {
    unsigned u = __builtin_bit_cast(unsigned, f);
    u += 0x7fffu + ((u >> 16) & 1u);          // RNE, inputs are finite
    return (unsigned short)(u >> 16);
}

// ---------------- Kernel 0: prep — emit X and W in GEMM-staging chunk order -----------
// (unchanged from R9 — verified.)
__global__ __launch_bounds__(256) void prep_kernel(
        const float* __restrict__ X, unsigned short* __restrict__ Xc,
        const float* __restrict__ W, unsigned short* __restrict__ Wc) {
    __shared__ float tile[32][33];
    const int bid = blockIdx.x;
    const int t = threadIdx.x;
    if (bid < 6144) {
        const int cg = bid * 4 + (t >> 6);      // global chunk id
        const int lane = t & 63;
        const int p = cg / 384, rem = cg - p * 384;
        const int kt = rem >> 4, c = rem & 15;
        const int kc = c >> 2, rg = c & 3;
        const int grow = p * 197 + rg * 64 + lane;
        uint4 u = (uint4){0, 0, 0, 0};
        if (grow < M_ROWS) {
            const float* src = X + (size_t)grow * K_DIM + kt * 32 + kc * 8;
            float4 a = *(const float4*)src;
            float4 b = *(const float4*)(src + 4);
            u.x = f2bf(a.x) | ((unsigned)f2bf(a.y) << 16);
            u.y = f2bf(a.z) | ((unsigned)f2bf(a.w) << 16);
            u.z = f2bf(b.x) | ((unsigned)f2bf(b.y) << 16);
            u.w = f2bf(b.z) | ((unsigned)f2bf(b.w) << 16);
        }
        *(uint4*)(Xc + (size_t)cg * 512 + lane * 8) = u;
        return;
    }
    const int b2 = bid - 6144;
    const int n0 = (b2 % 72) * 32, k0 = (b2 / 72) * 32;
    const int tx = t & 31, ty = t >> 5;
#pragma unroll
    for (int i = 0; i < 4; ++i)
        tile[ty + i * 8][tx] = W[(size_t)(k0 + ty + i * 8) * 2304 + n0 + tx];   // [klocal][nlocal]
    __syncthreads();
    if (t < 128) {
        const int kc = t >> 5, tx2 = t & 31;
        const int grp = n0 / 768, remn = n0 - grp * 768;
        const int h = remn >> 6, lh = remn & 63;    // 0 or 32
        const int kt = k0 >> 5;
        uint4 u;
        u.x = f2bf(tile[kc * 8 + 0][tx2]) | ((unsigned)f2bf(tile[kc * 8 + 1][tx2]) << 16);
        u.y = f2bf(tile[kc * 8 + 2][tx2]) | ((unsigned)f2bf(tile[kc * 8 + 3][tx2]) << 16);
        u.z = f2bf(tile[kc * 8 + 4][tx2]) | ((unsigned)f2bf(tile[kc * 8 + 5][tx2]) << 16);
        u.w = f2bf(tile[kc * 8 + 6][tx2]) | ((unsigned)f2bf(tile[kc * 8 + 7][tx2]) << 16);
        *(uint4*)(Wc + (size_t)(((h * 24 + kt) * 12) + kc * 3 + grp) * 512 + (lh + tx2) * 8) = u;
    }
}

// ---------------- Kernel 1: FUSED QKV-GEMM (register-direct) + attention --------------
// R11 (passed, 95.3us) with the K-loop's LDS machinery DELETED: fragments load
// straight from Xc/Wc global images into registers (byte-identical data to the LDS
// path — same chunk indexing). No staging DMA, no ds_reads, no vmcnt, NO BARRIERS for
// all 24 K-steps; waves decouple and the compiler software-pipelines the register
// loads. Reuse via L1 (waves sharing wm/wnn read identical 256B lines; per-kt set
// 28KB ~ L1) and per-XCD L2 (Wc 3.5MB resident; batch panel pinned by swizzle).
// A-frag (kt,quad,i): Xc[(bb*384 + kt*16 + quad*4 + wm)*512 + (i*16+l16)*8]
// B-frag (kt,quad,j): Wc[(h*288  + kt*12 + quad*3 + wnn)*512 + (j*16+l16)*8]
// GEMM wave grid 4M x 3N (wave tile 64x64, acc[4][4]); epilogue/attn verbatim R11.
// LDS (shorts): attn image only: Qs[0,14184) Ks[14184,28368) Vt[28368,42192)
// Ps[42192,68304). 136.6 KB, 1 block/CU.
__global__ __launch_bounds__(768) void fused_kernel(
        const unsigned short* __restrict__ Xc, const unsigned short* __restrict__ Wc,
        const float* __restrict__ bias, float* __restrict__ out) {
    __shared__ __align__(16) unsigned short L[68304];   // 136608 B

    const int t = threadIdx.x;
    const int w = t >> 6, lane = t & 63, quad = lane >> 4, l16 = lane & 15;
    const int wm = w / 3, wnn = w - wm * 3;     // 4M x 3N wave grid
    const int wrow0 = wm * 64;                  // GEMM rows owned
    const int wcol0 = wnn * 64;                 // GEMM cols owned

    // XCD-chunked bijective swizzle (768 = 8*96): each batch's 12 heads on one XCD
    const int lin = blockIdx.x;
    const int wg = (lin & 7) * 96 + (lin >> 3);
    const int bb = wg / 12, h = wg - bb * 12;

    // per-wave global fragment bases (element units)
    const unsigned short* pa = Xc + ((size_t)bb * 384 + quad * 4 + wm) * 512 + l16 * 8;
    const unsigned short* pb = Wc + ((size_t)h * 288 + quad * 3 + wnn) * 512 + l16 * 8;

#define LDA4(d, p) { d[0] = *(const bf16x8*)(p);        d[1] = *(const bf16x8*)((p) + 128); \
                     d[2] = *(const bf16x8*)((p) + 256); d[3] = *(const bf16x8*)((p) + 384); }
#define MFMA16(A, B)                                                                  \
    _Pragma("unroll")                                                                 \
    for (int i = 0; i < 4; ++i)                                                       \
        _Pragma("unroll")                                                             \
        for (int j = 0; j < 4; ++j)                                                   \
            acc[i][j] = __builtin_amdgcn_mfma_f32_16x16x32_bf16(A[i], B[j], acc[i][j], 0, 0, 0);

    f32x4 acc[4][4];
#pragma unroll
    for (int i = 0; i < 4; ++i)
#pragma unroll
        for (int j = 0; j < 4; ++j) acc[i][j] = (f32x4){0.f, 0.f, 0.f, 0.f};

    // software-pipelined K-loop: named double-buffered frag regs, all-static indexing.
    bf16x8 a0[4], b0[4], a1[4], b1[4];
    LDA4(a0, pa) LDA4(b0, pb)
#pragma unroll 3
    for (int s2 = 0; s2 < 12; ++s2) {
        // prefetch kt = 2*s2+1
        LDA4(a1, pa + 8192) LDA4(b1, pb + 6144)
        MFMA16(a0, b0)
        pa += 16384; pb += 12288;               // advance to kt = 2*s2+2
        if (s2 < 11) { LDA4(a0, pa) LDA4(b0, pb) }
        MFMA16(a1, b1)
    }
#undef LDA4
#undef MFMA16

    unsigned short* Qs = &L[0];       // [197][72]
    unsigned short* Ks = &L[14184];   // [197][72]
    unsigned short* Vt = &L[28368];   // [64][216] transposed
    unsigned short* Ps = &L[42192];   // 12 x 16 x 136

    // epilogue: bias, q-scale, scatter to Qs/Ks/Vt. which == wnn is WAVE-UNIFORM.
    {
        const float bscale = (wnn == 0) ? 0.125f : 1.0f;
#pragma unroll
        for (int j = 0; j < 4; ++j) {
            const int d = j * 16 + l16;             // 0..63
            const float bv = bias[wnn * 768 + h * 64 + d];
#pragma unroll
            for (int i = 0; i < 4; ++i) {
                const int rowb = wrow0 + i * 16 + quad * 4;
#pragma unroll
                for (int r = 0; r < 4; ++r) {
                    const int row = rowb + r;
                    if (row >= 197) continue;
                    const float val = (acc[i][j][r] + bv) * bscale;
                    if (wnn == 0)      Qs[row * 72 + d] = f2bf(val);
                    else if (wnn == 1) Ks[row * 72 + d] = f2bf(val);
                    else               Vt[d * 216 + row] = f2bf(val);
                }
            }
        }
    }
    // zero Vt pad cols 197..215 (PV reads them where p==0; avoid NaN*0)
    for (int idx = t; idx < 64 * 19; idx += 768) {
        int d = idx / 19, c = 197 + idx - d * 19;
        Vt[d * 216 + c] = 0;
    }
    __syncthreads();

    // ---------------- attention phase (proven structure; Q/K/V already in LDS) --------
    unsigned short* Pw = Ps + w * (16 * 136);

    for (int tile = w; tile < 13; tile += 12) {
        int rq = tile * 16 + l16;
        int tokq = rq < 197 ? rq : 196;
        bf16x8 aq0 = *(const bf16x8*)&Qs[tokq * 72 + quad * 8];
        bf16x8 aq1 = *(const bf16x8*)&Qs[tokq * 72 + 32 + quad * 8];

        // scores: 13 chunks of 16 kt-cols, K fragments from LDS
        f32x4 s[13];
        __builtin_amdgcn_s_setprio(1);
#pragma unroll
        for (int c = 0; c < 13; ++c) {
            int krow = c * 16 + l16;
            if (krow > 196) krow = 196;             // clamped read; masked below
            bf16x8 kb0 = *(const bf16x8*)&Ks[krow * 72 + quad * 8];
            bf16x8 kb1 = *(const bf16x8*)&Ks[krow * 72 + 32 + quad * 8];
            f32x4 zz = (f32x4){0.f, 0.f, 0.f, 0.f};
            zz = __builtin_amdgcn_mfma_f32_16x16x32_bf16(aq0, kb0, zz, 0, 0, 0);
            zz = __builtin_amdgcn_mfma_f32_16x16x32_bf16(aq1, kb1, zz, 0, 0, 0);
            s[c] = zz;
        }
        __builtin_amdgcn_s_setprio(0);
        if (l16 >= 5) { s[12][0] = -1e30f; s[12][1] = -1e30f; s[12][2] = -1e30f; s[12][3] = -1e30f; }

        // softmax over 208 cols (rows = quad*4+r, cols spread over l16)
        float mx[4], lsum[4];
#pragma unroll
        for (int r = 0; r < 4; ++r) {
            float m = s[0][r];
#pragma unroll
            for (int c = 1; c < 13; ++c) m = fmaxf(m, s[c][r]);
#pragma unroll
            for (int d = 1; d < 16; d <<= 1) m = fmaxf(m, __shfl_xor(m, d));
            mx[r] = m;
            lsum[r] = 0.f;
        }
#pragma unroll
        for (int c = 0; c < 13; ++c)
#pragma unroll
            for (int r = 0; r < 4; ++r) {
                float p = __expf(s[c][r] - mx[r]);
                s[c][r] = p;
                lsum[r] += p;
            }
#pragma unroll
        for (int r = 0; r < 4; ++r)
#pragma unroll
            for (int d = 1; d < 16; d <<= 1) lsum[r] += __shfl_xor(lsum[r], d);

        f32x4 o[4];
#pragma unroll
        for (int j = 0; j < 4; ++j) o[j] = (f32x4){0.f, 0.f, 0.f, 0.f};

        // PV pass 1: P cols 0..127 (same-wave LDS round trip, no barrier)
#pragma unroll
        for (int c = 0; c < 8; ++c)
#pragma unroll
            for (int r = 0; r < 4; ++r)
                Pw[(quad * 4 + r) * 136 + c * 16 + l16] = f2bf(s[c][r]);
        __builtin_amdgcn_s_setprio(1);
#pragma unroll
        for (int kc = 0; kc < 4; ++kc) {
            int kof = kc * 32 + quad * 8;
            bf16x8 ap = *(const bf16x8*)&Pw[l16 * 136 + kof];
#pragma unroll
            for (int j = 0; j < 4; ++j) {
                bf16x8 bv = *(const bf16x8*)&Vt[(j * 16 + l16) * 216 + kof];
                o[j] = __builtin_amdgcn_mfma_f32_16x16x32_bf16(ap, bv, o[j], 0, 0, 0);
            }
        }
        __builtin_amdgcn_s_setprio(0);
        // PV pass 2: P cols 128..207 -> buffer cols 0..79; cols 80..95 zeroed (p==0)
#pragma unroll
        for (int r = 0; r < 4; ++r)
            Pw[(quad * 4 + r) * 136 + 80 + l16] = 0;
#pragma unroll
        for (int c = 8; c < 13; ++c)
#pragma unroll
            for (int r = 0; r < 4; ++r)
                Pw[(quad * 4 + r) * 136 + (c - 8) * 16 + l16] = f2bf(s[c][r]);
        __builtin_amdgcn_s_setprio(1);
#pragma unroll
        for (int kc = 0; kc < 3; ++kc) {
            int kofA = kc * 32 + quad * 8;
            // kc==2, quad>=2 -> kt 208..223 where p==0 exactly; clamp LDS read in-range
            int kofB = (kc == 2 && quad >= 2) ? 0 : kofA;
            bf16x8 ap = *(const bf16x8*)&Pw[l16 * 136 + kofA];
#pragma unroll
            for (int j = 0; j < 4; ++j) {
                bf16x8 bv = *(const bf16x8*)&Vt[(j * 16 + l16) * 216 + 128 + kofB];
                o[j] = __builtin_amdgcn_mfma_f32_16x16x32_bf16(ap, bv, o[j], 0, 0, 0);
            }
        }
        __builtin_amdgcn_s_setprio(0);

        // epilogue: divide by l, store fp32 [B, tok, 768]
        int tokbase = tile * 16 + quad * 4;
#pragma unroll
        for (int r = 0; r < 4; ++r) {
            int tr = tokbase + r;
            if (tr >= 197) continue;
            float inv = 1.f / lsum[r];
#pragma unroll
            for (int j = 0; j < 4; ++j)
                out[((size_t)(bb * 197 + tr)) * 768 + h * 64 + j * 16 + l16] = o[j][r] * inv;
        }
    }
}

extern "C" void kernel_launch(void* const* d_in, const int* in_sizes, int n_in,
                              void* d_out, int out_size, void* d_ws, size_t ws_size,
                              hipStream_t stream) {
    const float* X    = (const float*)d_in[0];   // [64,197,768]
    const float* W    = (const float*)d_in[1];   // [768,2304]
    const float* bias = (const float*)d_in[2];   // [2304]
    float* out = (float*)d_out;                  // [64,197,768]

    // Xc and Wc (chunk-order staging images) live in d_ws
    unsigned short* Xc = (unsigned short*)d_ws;
    unsigned short* Wc = (unsigned short*)d_ws + XC_ELEMS;

    prep_kernel<<<7872, 256, 0, stream>>>(X, Xc, W, Wc);
    fused_kernel<<<768, 768, 0, stream>>>(Xc, Wc, bias, out);
}

// Round 13
// 206.739 us; speedup vs baseline: 1.0242x; 1.0242x over previous
//
#include <hip/hip_runtime.h>

#define M_ROWS 12608          // 64*197
#define K_DIM  768
// Xc: 64 panels x 24 kt x 16 chunks x 512 shorts (chunk = [lane64][k8]) = 25.2 MB
#define XC_ELEMS (64*24*16*512)
// Wc: 12 heads x 24 kt x 12 chunks x 512 shorts = 3.5 MB
#define WC_ELEMS (12*24*12*512)

typedef __bf16 bf16x8 __attribute__((ext_vector_type(8)));
typedef float  f32x4  __attribute__((ext_vector_type(4)));

__device__ __forceinline__ unsigned short f2bf(float f) {
    unsigned u = __builtin_bit_cast(unsigned, f);
    u += 0x7fffu + ((u >> 16) & 1u);          // RNE, inputs are finite
    return (unsigned short)(u >> 16);
}

__device__ __forceinline__ void gll16(const unsigned short* g, unsigned short* l) {
    __builtin_amdgcn_global_load_lds(
        (const __attribute__((address_space(1))) unsigned int*)g,
        (__attribute__((address_space(3))) unsigned int*)l, 16, 0, 0);
}

// ---------------- Kernel 0: prep — emit X and W in GEMM-staging chunk order -----------
// (unchanged from R9 — verified.)
__global__ __launch_bounds__(256) void prep_kernel(
        const float* __restrict__ X, unsigned short* __restrict__ Xc,
        const float* __restrict__ W, unsigned short* __restrict__ Wc) {
    __shared__ float tile[32][33];
    const int bid = blockIdx.x;
    const int t = threadIdx.x;
    if (bid < 6144) {
        const int cg = bid * 4 + (t >> 6);      // global chunk id
        const int lane = t & 63;
        const int p = cg / 384, rem = cg - p * 384;
        const int kt = rem >> 4, c = rem & 15;
        const int kc = c >> 2, rg = c & 3;
        const int grow = p * 197 + rg * 64 + lane;
        uint4 u = (uint4){0, 0, 0, 0};
        if (grow < M_ROWS) {
            const float* src = X + (size_t)grow * K_DIM + kt * 32 + kc * 8;
            float4 a = *(const float4*)src;
            float4 b = *(const float4*)(src + 4);
            u.x = f2bf(a.x) | ((unsigned)f2bf(a.y) << 16);
            u.y = f2bf(a.z) | ((unsigned)f2bf(a.w) << 16);
            u.z = f2bf(b.x) | ((unsigned)f2bf(b.y) << 16);
            u.w = f2bf(b.z) | ((unsigned)f2bf(b.w) << 16);
        }
        *(uint4*)(Xc + (size_t)cg * 512 + lane * 8) = u;
        return;
    }
    const int b2 = bid - 6144;
    const int n0 = (b2 % 72) * 32, k0 = (b2 / 72) * 32;
    const int tx = t & 31, ty = t >> 5;
#pragma unroll
    for (int i = 0; i < 4; ++i)
        tile[ty + i * 8][tx] = W[(size_t)(k0 + ty + i * 8) * 2304 + n0 + tx];   // [klocal][nlocal]
    __syncthreads();
    if (t < 128) {
        const int kc = t >> 5, tx2 = t & 31;
        const int grp = n0 / 768, remn = n0 - grp * 768;
        const int h = remn >> 6, lh = remn & 63;    // 0 or 32
        const int kt = k0 >> 5;
        uint4 u;
        u.x = f2bf(tile[kc * 8 + 0][tx2]) | ((unsigned)f2bf(tile[kc * 8 + 1][tx2]) << 16);
        u.y = f2bf(tile[kc * 8 + 2][tx2]) | ((unsigned)f2bf(tile[kc * 8 + 3][tx2]) << 16);
        u.z = f2bf(tile[kc * 8 + 4][tx2]) | ((unsigned)f2bf(tile[kc * 8 + 5][tx2]) << 16);
        u.w = f2bf(tile[kc * 8 + 6][tx2]) | ((unsigned)f2bf(tile[kc * 8 + 7][tx2]) << 16);
        *(uint4*)(Wc + (size_t)(((h * 24 + kt) * 12) + kc * 3 + grp) * 512 + (lh + tx2) * 8) = u;
    }
}

// ---------------- Kernel 1: FUSED per-head QKV-GEMM + attention, 208-row GEMM ---------
// R11 base (passed, 95.3us fused) with the M-padding waste removed: GEMM computes 208
// rows (13 tiles) instead of 256. Balanced decomposition: wm0 -> tiles 0-3 (rows
// 0-63), wm1 -> 4-6 (64-111), wm2 -> 7-9 (112-159), wm3 -> 10-12 (160-207).
// MFMA 192->156/kt (-19%), A-frag LDS reads 48->39/kt (-19%); per-SIMD MFMA load
// balances to 10/10/10/9 tiles (4-tile waves 0,1,2 land on different SIMDs).
// Epilogue: i==3 skipped for wm>=1 (rows owned by other waves); row<197 guards tile
// 12's tail. Staging/attn/LDS map byte-identical to R11.
// LDS (shorts): staging A dbuf [0,16384) + B dbuf [16384,28672) DEAD after GEMM;
// attn image aliases: Qs [0,14184) | Ks [14184,28368) | Vt [28368,42192) |
// Ps [42192,68304). 136.6 KB, 1 block/CU.
__global__ __launch_bounds__(768) void fused_kernel(
        const unsigned short* __restrict__ Xc, const unsigned short* __restrict__ Wc,
        const float* __restrict__ bias, float* __restrict__ out) {
    __shared__ __align__(16) unsigned short L[68304];   // 136608 B

    const int t = threadIdx.x;
    const int w = t >> 6, lane = t & 63, quad = lane >> 4, l16 = lane & 15;
    const int wm = w / 3, wnn = w - wm * 3;     // 4M x 3N wave grid
    const int wrow0 = (wm == 0) ? 0 : (48 * wm + 16);   // rows: 0 / 64 / 112 / 160
    const int wcol0 = wnn * 64;                 // GEMM cols owned

    // XCD-chunked bijective swizzle (768 = 8*96): each batch's 12 heads on one XCD
    const int lin = blockIdx.x;
    const int wg = (lin & 7) * 96 + (lin >> 3);
    const int bb = wg / 12, h = wg - bb * 12;

    // staging chunk table: chunks 0..15 = A (offset c*512, kstep 8192, dbuf 8192),
    // 16..27 = B (offset 16384+cb*512, kstep 6144, dbuf 6144). Wave w stages
    // {w, w+12, 24+w if w<4}; every chunk covered exactly once.
    const unsigned short* sgp[3];
    int sof[3], gst[3], bst[3];
    const int nst = (w < 4) ? 3 : 2;
    {
        const int clist[3] = {w, w + 12, 24 + w};
#pragma unroll
        for (int s = 0; s < 3; ++s) {
            const int c = clist[s];
            if (c < 16) {
                sgp[s] = Xc + ((size_t)bb * 384 + c) * 512 + lane * 8;
                sof[s] = c * 512; gst[s] = 8192; bst[s] = 8192;
            } else {
                const int cb = c - 16;
                sgp[s] = Wc + ((size_t)h * 288 + cb) * 512 + lane * 8;
                sof[s] = 16384 + cb * 512; gst[s] = 6144; bst[s] = 6144;
            }
        }
    }

    f32x4 acc[4][4];
#pragma unroll
    for (int i = 0; i < 4; ++i)
#pragma unroll
        for (int j = 0; j < 4; ++j) acc[i][j] = (f32x4){0.f, 0.f, 0.f, 0.f};

    // prologue: stage tile 0 into buf 0, land it
#pragma unroll
    for (int s = 0; s < 3; ++s)
        if (s < nst) gll16(sgp[s], &L[sof[s]]);
    asm volatile("s_waitcnt vmcnt(0)" ::: "memory");
    __builtin_amdgcn_s_barrier();
    asm volatile("" ::: "memory");

#pragma unroll 2
    for (int kt = 0; kt < 24; ++kt) {
        const int cur = kt & 1, nxt = cur ^ 1;

        // issue next tile's staging first; body overlaps its latency (skip dead tail)
        if (kt < 23) {
#pragma unroll
            for (int s = 0; s < 3; ++s)
                if (s < nst) gll16(sgp[s] + (size_t)(kt + 1) * gst[s], &L[sof[s] + nxt * bst[s]]);
        }

        const unsigned short* Ab = &L[cur * 8192];
        const unsigned short* Bb = &L[16384 + cur * 6144];
        bf16x8 af[4], bq[4];
#pragma unroll
        for (int i = 0; i < 4; ++i)
            if (wm == 0 || i < 3)
                af[i] = *(const bf16x8*)&Ab[quad * 2048 + (wrow0 + i * 16 + l16) * 8];
#pragma unroll
        for (int j = 0; j < 4; ++j)
            bq[j] = *(const bf16x8*)&Bb[quad * 1536 + (wcol0 + j * 16 + l16) * 8];

#pragma unroll
        for (int i = 0; i < 4; ++i)
            if (wm == 0 || i < 3)
#pragma unroll
                for (int j = 0; j < 4; ++j)
                    acc[i][j] = __builtin_amdgcn_mfma_f32_16x16x32_bf16(af[i], bq[j], acc[i][j], 0, 0, 0);

        asm volatile("s_waitcnt vmcnt(0)" ::: "memory");
        __builtin_amdgcn_s_barrier();
        asm volatile("" ::: "memory");
    }

    unsigned short* Qs = &L[0];       // [197][72]
    unsigned short* Ks = &L[14184];   // [197][72]
    unsigned short* Vt = &L[28368];   // [64][216] transposed
    unsigned short* Ps = &L[42192];   // 12 x 16 x 136

    // epilogue: bias, q-scale, scatter to Qs/Ks/Vt. which == wnn is WAVE-UNIFORM.
    // i==3 rows belong to other waves for wm>=1 (never MFMA'd here) -> skip.
    {
#pragma unroll
        for (int j = 0; j < 4; ++j) {
            const int d = j * 16 + l16;             // 0..63
            const float bv = bias[wnn * 768 + h * 64 + d];
#pragma unroll
            for (int i = 0; i < 4; ++i) {
                if (wm != 0 && i == 3) continue;
                const int rowb = wrow0 + i * 16 + quad * 4;
#pragma unroll
                for (int r = 0; r < 4; ++r) {
                    const int row = rowb + r;
                    if (row >= 197) continue;
                    float val = acc[i][j][r] + bv;
                    if (wnn == 0) {
                        Qs[row * 72 + d] = f2bf(val * 0.125f);
                    } else if (wnn == 1) {
                        Ks[row * 72 + d] = f2bf(val);
                    } else {
                        Vt[d * 216 + row] = f2bf(val);
                    }
                }
            }
        }
    }
    // zero Vt pad cols 197..215 (PV reads them where p==0; avoid NaN*0)
    for (int idx = t; idx < 64 * 19; idx += 768) {
        int d = idx / 19, c = 197 + idx - d * 19;
        Vt[d * 216 + c] = 0;
    }
    __syncthreads();

    // ---------------- attention phase (proven structure; Q/K/V already in LDS) --------
    unsigned short* Pw = Ps + w * (16 * 136);

    for (int tile = w; tile < 13; tile += 12) {
        int rq = tile * 16 + l16;
        int tokq = rq < 197 ? rq : 196;
        bf16x8 aq0 = *(const bf16x8*)&Qs[tokq * 72 + quad * 8];
        bf16x8 aq1 = *(const bf16x8*)&Qs[tokq * 72 + 32 + quad * 8];

        // scores: 13 chunks of 16 kt-cols, K fragments from LDS
        f32x4 s[13];
        __builtin_amdgcn_s_setprio(1);
#pragma unroll
        for (int c = 0; c < 13; ++c) {
            int krow = c * 16 + l16;
            if (krow > 196) krow = 196;             // clamped read; masked below
            bf16x8 kb0 = *(const bf16x8*)&Ks[krow * 72 + quad * 8];
            bf16x8 kb1 = *(const bf16x8*)&Ks[krow * 72 + 32 + quad * 8];
            f32x4 zz = (f32x4){0.f, 0.f, 0.f, 0.f};
            zz = __builtin_amdgcn_mfma_f32_16x16x32_bf16(aq0, kb0, zz, 0, 0, 0);
            zz = __builtin_amdgcn_mfma_f32_16x16x32_bf16(aq1, kb1, zz, 0, 0, 0);
            s[c] = zz;
        }
        __builtin_amdgcn_s_setprio(0);
        if (l16 >= 5) { s[12][0] = -1e30f; s[12][1] = -1e30f; s[12][2] = -1e30f; s[12][3] = -1e30f; }

        // softmax over 208 cols (rows = quad*4+r, cols spread over l16)
        float mx[4], lsum[4];
#pragma unroll
        for (int r = 0; r < 4; ++r) {
            float m = s[0][r];
#pragma unroll
            for (int c = 1; c < 13; ++c) m = fmaxf(m, s[c][r]);
#pragma unroll
            for (int d = 1; d < 16; d <<= 1) m = fmaxf(m, __shfl_xor(m, d));
            mx[r] = m;
            lsum[r] = 0.f;
        }
#pragma unroll
        for (int c = 0; c < 13; ++c)
#pragma unroll
            for (int r = 0; r < 4; ++r) {
                float p = __expf(s[c][r] - mx[r]);
                s[c][r] = p;
                lsum[r] += p;
            }
#pragma unroll
        for (int r = 0; r < 4; ++r)
#pragma unroll
            for (int d = 1; d < 16; d <<= 1) lsum[r] += __shfl_xor(lsum[r], d);

        f32x4 o[4];
#pragma unroll
        for (int j = 0; j < 4; ++j) o[j] = (f32x4){0.f, 0.f, 0.f, 0.f};

        // PV pass 1: P cols 0..127 (same-wave LDS round trip, no barrier)
#pragma unroll
        for (int c = 0; c < 8; ++c)
#pragma unroll
            for (int r = 0; r < 4; ++r)
                Pw[(quad * 4 + r) * 136 + c * 16 + l16] = f2bf(s[c][r]);
        __builtin_amdgcn_s_setprio(1);
#pragma unroll
        for (int kc = 0; kc < 4; ++kc) {
            int kof = kc * 32 + quad * 8;
            bf16x8 ap = *(const bf16x8*)&Pw[l16 * 136 + kof];
#pragma unroll
            for (int j = 0; j < 4; ++j) {
                bf16x8 bv = *(const bf16x8*)&Vt[(j * 16 + l16) * 216 + kof];
                o[j] = __builtin_amdgcn_mfma_f32_16x16x32_bf16(ap, bv, o[j], 0, 0, 0);
            }
        }
        __builtin_amdgcn_s_setprio(0);
        // PV pass 2: P cols 128..207 -> buffer cols 0..79; cols 80..95 zeroed (p==0)
#pragma unroll
        for (int r = 0; r < 4; ++r)
            Pw[(quad * 4 + r) * 136 + 80 + l16] = 0;
#pragma unroll
        for (int c = 8; c < 13; ++c)
#pragma unroll
            for (int r = 0; r < 4; ++r)
                Pw[(quad * 4 + r) * 136 + (c - 8) * 16 + l16] = f2bf(s[c][r]);
        __builtin_amdgcn_s_setprio(1);
#pragma unroll
        for (int kc = 0; kc < 3; ++kc) {
            int kofA = kc * 32 + quad * 8;
            // kc==2, quad>=2 -> kt 208..223 where p==0 exactly; clamp LDS read in-range
            int kofB = (kc == 2 && quad >= 2) ? 0 : kofA;
            bf16x8 ap = *(const bf16x8*)&Pw[l16 * 136 + kofA];
#pragma unroll
            for (int j = 0; j < 4; ++j) {
                bf16x8 bv = *(const bf16x8*)&Vt[(j * 16 + l16) * 216 + 128 + kofB];
                o[j] = __builtin_amdgcn_mfma_f32_16x16x32_bf16(ap, bv, o[j], 0, 0, 0);
            }
        }
        __builtin_amdgcn_s_setprio(0);

        // epilogue: divide by l, store fp32 [B, tok, 768]
        int tokbase = tile * 16 + quad * 4;
#pragma unroll
        for (int r = 0; r < 4; ++r) {
            int tr = tokbase + r;
            if (tr >= 197) continue;
            float inv = 1.f / lsum[r];
#pragma unroll
            for (int j = 0; j < 4; ++j)
                out[((size_t)(bb * 197 + tr)) * 768 + h * 64 + j * 16 + l16] = o[j][r] * inv;
        }
    }
}

extern "C" void kernel_launch(void* const* d_in, const int* in_sizes, int n_in,
                              void* d_out, int out_size, void* d_ws, size_t ws_size,
                              hipStream_t stream) {
    const float* X    = (const float*)d_in[0];   // [64,197,768]
    const float* W    = (const float*)d_in[1];   // [768,2304]
    const float* bias = (const float*)d_in[2];   // [2304]
    float* out = (float*)d_out;                  // [64,197,768]

    // Xc and Wc (chunk-order staging images) live in d_ws
    unsigned short* Xc = (unsigned short*)d_ws;
    unsigned short* Wc = (unsigned short*)d_ws + XC_ELEMS;

    prep_kernel<<<7872, 256, 0, stream>>>(X, Xc, W, Wc);
    fused_kernel<<<768, 768, 0, stream>>>(Xc, Wc, bias, out);
}

// Round 14
// 205.530 us; speedup vs baseline: 1.0302x; 1.0059x over previous
//
#include <hip/hip_runtime.h>

#define M_ROWS 12608          // 64*197
#define K_DIM  768
// Xc: 64 panels x 24 kt x 16 chunks x 512 shorts (chunk = [lane64][k8]) = 25.2 MB
#define XC_ELEMS (64*24*16*512)
// Wc: 12 heads x 24 kt x 12 chunks x 512 shorts = 3.5 MB
#define WC_ELEMS (12*24*12*512)

typedef __bf16 bf16x8 __attribute__((ext_vector_type(8)));
typedef float  f32x4  __attribute__((ext_vector_type(4)));

__device__ __forceinline__ unsigned short f2bf(float f) {
    unsigned u = __builtin_bit_cast(unsigned, f);
    u += 0x7fffu + ((u >> 16) & 1u);          // RNE, inputs are finite
    return (unsigned short)(u >> 16);
}

__device__ __forceinline__ void gll16(const unsigned short* g, unsigned short* l) {
    __builtin_amdgcn_global_load_lds(
        (const __attribute__((address_space(1))) unsigned int*)g,
        (__attribute__((address_space(3))) unsigned int*)l, 16, 0, 0);
}

// ---------------- Kernel 0: prep — emit X and W in GEMM-staging chunk order -----------
// (unchanged from R9 — verified.)
__global__ __launch_bounds__(256) void prep_kernel(
        const float* __restrict__ X, unsigned short* __restrict__ Xc,
        const float* __restrict__ W, unsigned short* __restrict__ Wc) {
    __shared__ float tile[32][33];
    const int bid = blockIdx.x;
    const int t = threadIdx.x;
    if (bid < 6144) {
        const int cg = bid * 4 + (t >> 6);      // global chunk id
        const int lane = t & 63;
        const int p = cg / 384, rem = cg - p * 384;
        const int kt = rem >> 4, c = rem & 15;
        const int kc = c >> 2, rg = c & 3;
        const int grow = p * 197 + rg * 64 + lane;
        uint4 u = (uint4){0, 0, 0, 0};
        if (grow < M_ROWS) {
            const float* src = X + (size_t)grow * K_DIM + kt * 32 + kc * 8;
            float4 a = *(const float4*)src;
            float4 b = *(const float4*)(src + 4);
            u.x = f2bf(a.x) | ((unsigned)f2bf(a.y) << 16);
            u.y = f2bf(a.z) | ((unsigned)f2bf(a.w) << 16);
            u.z = f2bf(b.x) | ((unsigned)f2bf(b.y) << 16);
            u.w = f2bf(b.z) | ((unsigned)f2bf(b.w) << 16);
        }
        *(uint4*)(Xc + (size_t)cg * 512 + lane * 8) = u;
        return;
    }
    const int b2 = bid - 6144;
    const int n0 = (b2 % 72) * 32, k0 = (b2 / 72) * 32;
    const int tx = t & 31, ty = t >> 5;
#pragma unroll
    for (int i = 0; i < 4; ++i)
        tile[ty + i * 8][tx] = W[(size_t)(k0 + ty + i * 8) * 2304 + n0 + tx];   // [klocal][nlocal]
    __syncthreads();
    if (t < 128) {
        const int kc = t >> 5, tx2 = t & 31;
        const int grp = n0 / 768, remn = n0 - grp * 768;
        const int h = remn >> 6, lh = remn & 63;    // 0 or 32
        const int kt = k0 >> 5;
        uint4 u;
        u.x = f2bf(tile[kc * 8 + 0][tx2]) | ((unsigned)f2bf(tile[kc * 8 + 1][tx2]) << 16);
        u.y = f2bf(tile[kc * 8 + 2][tx2]) | ((unsigned)f2bf(tile[kc * 8 + 3][tx2]) << 16);
        u.z = f2bf(tile[kc * 8 + 4][tx2]) | ((unsigned)f2bf(tile[kc * 8 + 5][tx2]) << 16);
        u.w = f2bf(tile[kc * 8 + 6][tx2]) | ((unsigned)f2bf(tile[kc * 8 + 7][tx2]) << 16);
        *(uint4*)(Wc + (size_t)(((h * 24 + kt) * 12) + kc * 3 + grp) * 512 + (lh + tx2) * 8) = u;
    }
}

// ---------------- Kernel 1: FUSED per-head QKV-GEMM + attention, 12 waves -------------
// R11 kernel (passed, 95.3us) with ONE change: Ps row stride 136 -> 140 shorts.
// Stride-136 P-stores were a 4-way bank conflict (quad term: 272dw = 16 mod 32 ->
// quads {0,16,0,16} collide pairwise) = the session-constant 2.66M SQ_LDS_BANK_CONFLICT.
// Stride 140: quad*280dw = 24*quad mod 32 -> {0,24,16,8}, four disjoint 8-bank groups
// covering all 32 banks -> conflict-free stores.
// LDS (shorts): staging A dbuf [0,16384) + B dbuf [16384,28672) DEAD after GEMM;
// attn image aliases: Qs [0,14184) | Ks [14184,28368) | Vt [28368,42192) |
// Ps [42192,69072) (12 x 16 x 140). 138.1 KB, 1 block/CU.
__global__ __launch_bounds__(768) void fused_kernel(
        const unsigned short* __restrict__ Xc, const unsigned short* __restrict__ Wc,
        const float* __restrict__ bias, float* __restrict__ out) {
    __shared__ __align__(16) unsigned short L[69072];   // 138144 B

    const int t = threadIdx.x;
    const int w = t >> 6, lane = t & 63, quad = lane >> 4, l16 = lane & 15;
    const int wm = w / 3, wnn = w - wm * 3;     // 4M x 3N wave grid
    const int wrow0 = wm * 64;                  // GEMM rows owned
    const int wcol0 = wnn * 64;                 // GEMM cols owned

    // XCD-chunked bijective swizzle (768 = 8*96): each batch's 12 heads on one XCD
    const int lin = blockIdx.x;
    const int wg = (lin & 7) * 96 + (lin >> 3);
    const int bb = wg / 12, h = wg - bb * 12;

    // staging chunk table: chunks 0..15 = A (offset c*512, kstep 8192, dbuf 8192),
    // 16..27 = B (offset 16384+cb*512, kstep 6144, dbuf 6144). Wave w stages
    // {w, w+12, 24+w if w<4}; every chunk covered exactly once.
    const unsigned short* sgp[3];
    int sof[3], gst[3], bst[3];
    const int nst = (w < 4) ? 3 : 2;
    {
        const int clist[3] = {w, w + 12, 24 + w};
#pragma unroll
        for (int s = 0; s < 3; ++s) {
            const int c = clist[s];
            if (c < 16) {
                sgp[s] = Xc + ((size_t)bb * 384 + c) * 512 + lane * 8;
                sof[s] = c * 512; gst[s] = 8192; bst[s] = 8192;
            } else {
                const int cb = c - 16;
                sgp[s] = Wc + ((size_t)h * 288 + cb) * 512 + lane * 8;
                sof[s] = 16384 + cb * 512; gst[s] = 6144; bst[s] = 6144;
            }
        }
    }

    f32x4 acc[4][4];
#pragma unroll
    for (int i = 0; i < 4; ++i)
#pragma unroll
        for (int j = 0; j < 4; ++j) acc[i][j] = (f32x4){0.f, 0.f, 0.f, 0.f};

    // prologue: stage tile 0 into buf 0, land it
#pragma unroll
    for (int s = 0; s < 3; ++s)
        if (s < nst) gll16(sgp[s], &L[sof[s]]);
    asm volatile("s_waitcnt vmcnt(0)" ::: "memory");
    __builtin_amdgcn_s_barrier();
    asm volatile("" ::: "memory");

#pragma unroll 2
    for (int kt = 0; kt < 24; ++kt) {
        const int cur = kt & 1, nxt = cur ^ 1;
        const int skt = (kt + 1 < 24 ? kt + 1 : 0);   // tail: dummy restage (dead)

        // issue next tile's staging first; body overlaps its latency
#pragma unroll
        for (int s = 0; s < 3; ++s)
            if (s < nst) gll16(sgp[s] + (size_t)skt * gst[s], &L[sof[s] + nxt * bst[s]]);

        const unsigned short* Ab = &L[cur * 8192];
        const unsigned short* Bb = &L[16384 + cur * 6144];
        bf16x8 af[4], bq[4];
#pragma unroll
        for (int i = 0; i < 4; ++i)
            af[i] = *(const bf16x8*)&Ab[quad * 2048 + (wrow0 + i * 16 + l16) * 8];
#pragma unroll
        for (int j = 0; j < 4; ++j)
            bq[j] = *(const bf16x8*)&Bb[quad * 1536 + (wcol0 + j * 16 + l16) * 8];

#pragma unroll
        for (int i = 0; i < 4; ++i)
#pragma unroll
            for (int j = 0; j < 4; ++j)
                acc[i][j] = __builtin_amdgcn_mfma_f32_16x16x32_bf16(af[i], bq[j], acc[i][j], 0, 0, 0);

        asm volatile("s_waitcnt vmcnt(0)" ::: "memory");
        __builtin_amdgcn_s_barrier();
        asm volatile("" ::: "memory");
    }

    unsigned short* Qs = &L[0];       // [197][72]
    unsigned short* Ks = &L[14184];   // [197][72]
    unsigned short* Vt = &L[28368];   // [64][216] transposed
    unsigned short* Ps = &L[42192];   // 12 x 16 x 140

    // epilogue: bias, q-scale, scatter to Qs/Ks/Vt. which == wnn is WAVE-UNIFORM.
    {
        const float bscale = (wnn == 0) ? 0.125f : 1.0f;
#pragma unroll
        for (int j = 0; j < 4; ++j) {
            const int d = j * 16 + l16;             // 0..63
            const float bv = bias[wnn * 768 + h * 64 + d];
#pragma unroll
            for (int i = 0; i < 4; ++i) {
                const int rowb = wrow0 + i * 16 + quad * 4;
#pragma unroll
                for (int r = 0; r < 4; ++r) {
                    const int row = rowb + r;
                    if (row >= 197) continue;
                    const float val = (acc[i][j][r] + bv) * bscale;
                    if (wnn == 0)      Qs[row * 72 + d] = f2bf(val);
                    else if (wnn == 1) Ks[row * 72 + d] = f2bf(val);
                    else               Vt[d * 216 + row] = f2bf(val);
                }
            }
        }
    }
    // zero Vt pad cols 197..215 (PV reads them where p==0; avoid NaN*0)
    for (int idx = t; idx < 64 * 19; idx += 768) {
        int d = idx / 19, c = 197 + idx - d * 19;
        Vt[d * 216 + c] = 0;
    }
    __syncthreads();

    // ---------------- attention phase (proven structure; Q/K/V already in LDS) --------
    unsigned short* Pw = Ps + w * (16 * 140);

    for (int tile = w; tile < 13; tile += 12) {
        int rq = tile * 16 + l16;
        int tokq = rq < 197 ? rq : 196;
        bf16x8 aq0 = *(const bf16x8*)&Qs[tokq * 72 + quad * 8];
        bf16x8 aq1 = *(const bf16x8*)&Qs[tokq * 72 + 32 + quad * 8];

        // scores: 13 chunks of 16 kt-cols, K fragments from LDS
        f32x4 s[13];
        __builtin_amdgcn_s_setprio(1);
#pragma unroll
        for (int c = 0; c < 13; ++c) {
            int krow = c * 16 + l16;
            if (krow > 196) krow = 196;             // clamped read; masked below
            bf16x8 kb0 = *(const bf16x8*)&Ks[krow * 72 + quad * 8];
            bf16x8 kb1 = *(const bf16x8*)&Ks[krow * 72 + 32 + quad * 8];
            f32x4 zz = (f32x4){0.f, 0.f, 0.f, 0.f};
            zz = __builtin_amdgcn_mfma_f32_16x16x32_bf16(aq0, kb0, zz, 0, 0, 0);
            zz = __builtin_amdgcn_mfma_f32_16x16x32_bf16(aq1, kb1, zz, 0, 0, 0);
            s[c] = zz;
        }
        __builtin_amdgcn_s_setprio(0);
        if (l16 >= 5) { s[12][0] = -1e30f; s[12][1] = -1e30f; s[12][2] = -1e30f; s[12][3] = -1e30f; }

        // softmax over 208 cols (rows = quad*4+r, cols spread over l16)
        float mx[4], lsum[4];
#pragma unroll
        for (int r = 0; r < 4; ++r) {
            float m = s[0][r];
#pragma unroll
            for (int c = 1; c < 13; ++c) m = fmaxf(m, s[c][r]);
#pragma unroll
            for (int d = 1; d < 16; d <<= 1) m = fmaxf(m, __shfl_xor(m, d));
            mx[r] = m;
            lsum[r] = 0.f;
        }
#pragma unroll
        for (int c = 0; c < 13; ++c)
#pragma unroll
            for (int r = 0; r < 4; ++r) {
                float p = __expf(s[c][r] - mx[r]);
                s[c][r] = p;
                lsum[r] += p;
            }
#pragma unroll
        for (int r = 0; r < 4; ++r)
#pragma unroll
            for (int d = 1; d < 16; d <<= 1) lsum[r] += __shfl_xor(lsum[r], d);

        f32x4 o[4];
#pragma unroll
        for (int j = 0; j < 4; ++j) o[j] = (f32x4){0.f, 0.f, 0.f, 0.f};

        // PV pass 1: P cols 0..127 (same-wave LDS round trip, no barrier)
#pragma unroll
        for (int c = 0; c < 8; ++c)
#pragma unroll
            for (int r = 0; r < 4; ++r)
                Pw[(quad * 4 + r) * 140 + c * 16 + l16] = f2bf(s[c][r]);
        __builtin_amdgcn_s_setprio(1);
#pragma unroll
        for (int kc = 0; kc < 4; ++kc) {
            int kof = kc * 32 + quad * 8;
            bf16x8 ap = *(const bf16x8*)&Pw[l16 * 140 + kof];
#pragma unroll
            for (int j = 0; j < 4; ++j) {
                bf16x8 bv = *(const bf16x8*)&Vt[(j * 16 + l16) * 216 + kof];
                o[j] = __builtin_amdgcn_mfma_f32_16x16x32_bf16(ap, bv, o[j], 0, 0, 0);
            }
        }
        __builtin_amdgcn_s_setprio(0);
        // PV pass 2: P cols 128..207 -> buffer cols 0..79; cols 80..95 zeroed (p==0)
#pragma unroll
        for (int r = 0; r < 4; ++r)
            Pw[(quad * 4 + r) * 140 + 80 + l16] = 0;
#pragma unroll
        for (int c = 8; c < 13; ++c)
#pragma unroll
            for (int r = 0; r < 4; ++r)
                Pw[(quad * 4 + r) * 140 + (c - 8) * 16 + l16] = f2bf(s[c][r]);
        __builtin_amdgcn_s_setprio(1);
#pragma unroll
        for (int kc = 0; kc < 3; ++kc) {
            int kofA = kc * 32 + quad * 8;
            // kc==2, quad>=2 -> kt 208..223 where p==0 exactly; clamp LDS read in-range
            int kofB = (kc == 2 && quad >= 2) ? 0 : kofA;
            bf16x8 ap = *(const bf16x8*)&Pw[l16 * 140 + kofA];
#pragma unroll
            for (int j = 0; j < 4; ++j) {
                bf16x8 bv = *(const bf16x8*)&Vt[(j * 16 + l16) * 216 + 128 + kofB];
                o[j] = __builtin_amdgcn_mfma_f32_16x16x32_bf16(ap, bv, o[j], 0, 0, 0);
            }
        }
        __builtin_amdgcn_s_setprio(0);

        // epilogue: divide by l, store fp32 [B, tok, 768]
        int tokbase = tile * 16 + quad * 4;
#pragma unroll
        for (int r = 0; r < 4; ++r) {
            int tr = tokbase + r;
            if (tr >= 197) continue;
            float inv = 1.f / lsum[r];
#pragma unroll
            for (int j = 0; j < 4; ++j)
                out[((size_t)(bb * 197 + tr)) * 768 + h * 64 + j * 16 + l16] = o[j][r] * inv;
        }
    }
}

extern "C" void kernel_launch(void* const* d_in, const int* in_sizes, int n_in,
                              void* d_out, int out_size, void* d_ws, size_t ws_size,
                              hipStream_t stream) {
    const float* X    = (const float*)d_in[0];   // [64,197,768]
    const float* W    = (const float*)d_in[1];   // [768,2304]
    const float* bias = (const float*)d_in[2];   // [2304]
    float* out = (float*)d_out;                  // [64,197,768]

    // Xc and Wc (chunk-order staging images) live in d_ws
    unsigned short* Xc = (unsigned short*)d_ws;
    unsigned short* Wc = (unsigned short*)d_ws + XC_ELEMS;

    prep_kernel<<<7872, 256, 0, stream>>>(X, Xc, W, Wc);
    fused_kernel<<<768, 768, 0, stream>>>(Xc, Wc, bias, out);
}

// Round 15
// 186.174 us; speedup vs baseline: 1.1373x; 1.1040x over previous
//
#include <hip/hip_runtime.h>

#define M_ROWS 12608          // 64*197
#define K_DIM  768
// Xc: 64 panels x 24 kt x 16 chunks x 512 shorts (chunk = [lane64][k8]) = 25.2 MB
#define XC_ELEMS (64*24*16*512)
// Wc: 12 heads x 24 kt x 12 chunks x 512 shorts = 3.5 MB
#define WC_ELEMS (12*24*12*512)

typedef __bf16 bf16x8 __attribute__((ext_vector_type(8)));
typedef float  f32x4  __attribute__((ext_vector_type(4)));

__device__ __forceinline__ unsigned short f2bf(float f) {
    unsigned u = __builtin_bit_cast(unsigned, f);
    u += 0x7fffu + ((u >> 16) & 1u);          // RNE, inputs are finite
    return (unsigned short)(u >> 16);
}

__device__ __forceinline__ void gll16(const unsigned short* g, unsigned short* l) {
    __builtin_amdgcn_global_load_lds(
        (const __attribute__((address_space(1))) unsigned int*)g,
        (__attribute__((address_space(3))) unsigned int*)l, 16, 0, 0);
}

// ---------------- Kernel 0: prep — emit X and W in GEMM-staging chunk order -----------
// v2: X-part now LDS-staged so BOTH sides are clean (R9's X-part read 64 lanes x 32B
// at 3KB stride — scattered, ~4x line re-fetch, inferred ~40us).
// Blocks 0..1023: (p, rg, kq) tile = 64 rows x 192 floats.
//   Phase 1: coalesced row-segment reads (768B contiguous per row) -> bf16 -> LDS
//   [64][200] (stride 200 shorts = 100 dw = 4 mod 32 -> phase-2 column b128 reads are
//   conflict-free: 8 lanes per 4-bank group). Zero-fill rows with grow >= M_ROWS
//   (same semantics as R9).
//   Phase 2: 24 chunks (ktl 0..5 x kc 0..3), each: lane l reads LDS[l][ktl*32+kc*8]
//   (16B) -> 1KB contiguous coalesced global store. Chunk layout byte-identical to R9:
//   Xc[(p*384 + kt*16 + kc*4 + rg)*512 + l*8].
// Blocks 1024..2751: wtrans (verbatim R9). Wc[(h*24+kt)*12 + kc*3 + grp].
__global__ __launch_bounds__(256) void prep_kernel(
        const float* __restrict__ X, unsigned short* __restrict__ Xc,
        const float* __restrict__ W, unsigned short* __restrict__ Wc) {
    __shared__ __align__(16) unsigned short Lp[64 * 200];   // 25.6 KB
    __shared__ float tile[32][33];
    const int bid = blockIdx.x;
    const int t = threadIdx.x;
    if (bid < 1024) {
        const int p = bid >> 4, sub = bid & 15;
        const int rg = sub >> 2, kq = sub & 3;          // k-quarter: kt kq*6..kq*6+5
        const int w = t >> 6, lane = t & 63;

        // phase 1: read 64 x 192 floats coalesced, convert, stage to LDS
#pragma unroll
        for (int i = 0; i < 12; ++i) {
            const int f4 = i * 256 + t;                 // 0..3071 float4 units
            const int row = f4 / 48;                    // 48 float4 per row
            const int col4 = f4 - row * 48;
            const size_t grow = (size_t)p * 197 + rg * 64 + row;
            float4 v = (float4){0.f, 0.f, 0.f, 0.f};
            if (grow < M_ROWS)
                v = *(const float4*)(X + grow * K_DIM + kq * 192 + col4 * 4);
            ushort4 s;
            s.x = f2bf(v.x); s.y = f2bf(v.y); s.z = f2bf(v.z); s.w = f2bf(v.w);
            *(ushort4*)&Lp[row * 200 + col4 * 4] = s;
        }
        __syncthreads();

        // phase 2: 24 chunks; wave w writes chunks w*6..w*6+5
#pragma unroll
        for (int s = 0; s < 6; ++s) {
            const int cc = w * 6 + s;                   // 0..23
            const int ktl = cc >> 2, kc = cc & 3;
            const int kt = kq * 6 + ktl;
            bf16x8 v = *(const bf16x8*)&Lp[lane * 200 + ktl * 32 + kc * 8];
            *(bf16x8*)(Xc + ((size_t)p * 384 + kt * 16 + kc * 4 + rg) * 512 + lane * 8) = v;
        }
        return;
    }
    const int b2 = bid - 1024;
    const int n0 = (b2 % 72) * 32, k0 = (b2 / 72) * 32;
    const int tx = t & 31, ty = t >> 5;
#pragma unroll
    for (int i = 0; i < 4; ++i)
        tile[ty + i * 8][tx] = W[(size_t)(k0 + ty + i * 8) * 2304 + n0 + tx];   // [klocal][nlocal]
    __syncthreads();
    if (t < 128) {
        const int kc = t >> 5, tx2 = t & 31;
        const int grp = n0 / 768, remn = n0 - grp * 768;
        const int h = remn >> 6, lh = remn & 63;    // 0 or 32
        const int kt = k0 >> 5;
        uint4 u;
        u.x = f2bf(tile[kc * 8 + 0][tx2]) | ((unsigned)f2bf(tile[kc * 8 + 1][tx2]) << 16);
        u.y = f2bf(tile[kc * 8 + 2][tx2]) | ((unsigned)f2bf(tile[kc * 8 + 3][tx2]) << 16);
        u.z = f2bf(tile[kc * 8 + 4][tx2]) | ((unsigned)f2bf(tile[kc * 8 + 5][tx2]) << 16);
        u.w = f2bf(tile[kc * 8 + 6][tx2]) | ((unsigned)f2bf(tile[kc * 8 + 7][tx2]) << 16);
        *(uint4*)(Wc + (size_t)(((h * 24 + kt) * 12) + kc * 3 + grp) * 512 + (lh + tx2) * 8) = u;
    }
}

// ---------------- Kernel 1: FUSED per-head QKV-GEMM + attention, 12 waves -------------
// EXACT R11 kernel (best fused variant: 95.3us, passed). Ps stride 136 restored
// (R14's 140 regressed 4.7us; conflicts are not the lever).
// LDS (shorts): staging A dbuf [0,16384) + B dbuf [16384,28672) DEAD after GEMM;
// attn image aliases: Qs [0,14184) | Ks [14184,28368) | Vt [28368,42192) |
// Ps [42192,68304). 136.6 KB, 1 block/CU.
__global__ __launch_bounds__(768) void fused_kernel(
        const unsigned short* __restrict__ Xc, const unsigned short* __restrict__ Wc,
        const float* __restrict__ bias, float* __restrict__ out) {
    __shared__ __align__(16) unsigned short L[68304];   // 136608 B

    const int t = threadIdx.x;
    const int w = t >> 6, lane = t & 63, quad = lane >> 4, l16 = lane & 15;
    const int wm = w / 3, wnn = w - wm * 3;     // 4M x 3N wave grid
    const int wrow0 = wm * 64;                  // GEMM rows owned
    const int wcol0 = wnn * 64;                 // GEMM cols owned

    // XCD-chunked bijective swizzle (768 = 8*96): each batch's 12 heads on one XCD
    const int lin = blockIdx.x;
    const int wg = (lin & 7) * 96 + (lin >> 3);
    const int bb = wg / 12, h = wg - bb * 12;

    // staging chunk table: chunks 0..15 = A (offset c*512, kstep 8192, dbuf 8192),
    // 16..27 = B (offset 16384+cb*512, kstep 6144, dbuf 6144). Wave w stages
    // {w, w+12, 24+w if w<4}; every chunk covered exactly once.
    const unsigned short* sgp[3];
    int sof[3], gst[3], bst[3];
    const int nst = (w < 4) ? 3 : 2;
    {
        const int clist[3] = {w, w + 12, 24 + w};
#pragma unroll
        for (int s = 0; s < 3; ++s) {
            const int c = clist[s];
            if (c < 16) {
                sgp[s] = Xc + ((size_t)bb * 384 + c) * 512 + lane * 8;
                sof[s] = c * 512; gst[s] = 8192; bst[s] = 8192;
            } else {
                const int cb = c - 16;
                sgp[s] = Wc + ((size_t)h * 288 + cb) * 512 + lane * 8;
                sof[s] = 16384 + cb * 512; gst[s] = 6144; bst[s] = 6144;
            }
        }
    }

    f32x4 acc[4][4];
#pragma unroll
    for (int i = 0; i < 4; ++i)
#pragma unroll
        for (int j = 0; j < 4; ++j) acc[i][j] = (f32x4){0.f, 0.f, 0.f, 0.f};

    // prologue: stage tile 0 into buf 0, land it
#pragma unroll
    for (int s = 0; s < 3; ++s)
        if (s < nst) gll16(sgp[s], &L[sof[s]]);
    asm volatile("s_waitcnt vmcnt(0)" ::: "memory");
    __builtin_amdgcn_s_barrier();
    asm volatile("" ::: "memory");

#pragma unroll 2
    for (int kt = 0; kt < 24; ++kt) {
        const int cur = kt & 1, nxt = cur ^ 1;
        const int skt = (kt + 1 < 24 ? kt + 1 : 0);   // tail: dummy restage (dead)

        // issue next tile's staging first; body overlaps its latency
#pragma unroll
        for (int s = 0; s < 3; ++s)
            if (s < nst) gll16(sgp[s] + (size_t)skt * gst[s], &L[sof[s] + nxt * bst[s]]);

        const unsigned short* Ab = &L[cur * 8192];
        const unsigned short* Bb = &L[16384 + cur * 6144];
        bf16x8 af[4], bq[4];
#pragma unroll
        for (int i = 0; i < 4; ++i)
            af[i] = *(const bf16x8*)&Ab[quad * 2048 + (wrow0 + i * 16 + l16) * 8];
#pragma unroll
        for (int j = 0; j < 4; ++j)
            bq[j] = *(const bf16x8*)&Bb[quad * 1536 + (wcol0 + j * 16 + l16) * 8];

#pragma unroll
        for (int i = 0; i < 4; ++i)
#pragma unroll
            for (int j = 0; j < 4; ++j)
                acc[i][j] = __builtin_amdgcn_mfma_f32_16x16x32_bf16(af[i], bq[j], acc[i][j], 0, 0, 0);

        asm volatile("s_waitcnt vmcnt(0)" ::: "memory");
        __builtin_amdgcn_s_barrier();
        asm volatile("" ::: "memory");
    }

    unsigned short* Qs = &L[0];       // [197][72]
    unsigned short* Ks = &L[14184];   // [197][72]
    unsigned short* Vt = &L[28368];   // [64][216] transposed
    unsigned short* Ps = &L[42192];   // 12 x 16 x 136

    // epilogue: bias, q-scale, scatter to Qs/Ks/Vt. which == wnn is WAVE-UNIFORM.
    {
        const float bscale = (wnn == 0) ? 0.125f : 1.0f;
#pragma unroll
        for (int j = 0; j < 4; ++j) {
            const int d = j * 16 + l16;             // 0..63
            const float bv = bias[wnn * 768 + h * 64 + d];
#pragma unroll
            for (int i = 0; i < 4; ++i) {
                const int rowb = wrow0 + i * 16 + quad * 4;
#pragma unroll
                for (int r = 0; r < 4; ++r) {
                    const int row = rowb + r;
                    if (row >= 197) continue;
                    const float val = (acc[i][j][r] + bv) * bscale;
                    if (wnn == 0)      Qs[row * 72 + d] = f2bf(val);
                    else if (wnn == 1) Ks[row * 72 + d] = f2bf(val);
                    else               Vt[d * 216 + row] = f2bf(val);
                }
            }
        }
    }
    // zero Vt pad cols 197..215 (PV reads them where p==0; avoid NaN*0)
    for (int idx = t; idx < 64 * 19; idx += 768) {
        int d = idx / 19, c = 197 + idx - d * 19;
        Vt[d * 216 + c] = 0;
    }
    __syncthreads();

    // ---------------- attention phase (proven structure; Q/K/V already in LDS) --------
    unsigned short* Pw = Ps + w * (16 * 136);

    for (int tile = w; tile < 13; tile += 12) {
        int rq = tile * 16 + l16;
        int tokq = rq < 197 ? rq : 196;
        bf16x8 aq0 = *(const bf16x8*)&Qs[tokq * 72 + quad * 8];
        bf16x8 aq1 = *(const bf16x8*)&Qs[tokq * 72 + 32 + quad * 8];

        // scores: 13 chunks of 16 kt-cols, K fragments from LDS
        f32x4 s[13];
        __builtin_amdgcn_s_setprio(1);
#pragma unroll
        for (int c = 0; c < 13; ++c) {
            int krow = c * 16 + l16;
            if (krow > 196) krow = 196;             // clamped read; masked below
            bf16x8 kb0 = *(const bf16x8*)&Ks[krow * 72 + quad * 8];
            bf16x8 kb1 = *(const bf16x8*)&Ks[krow * 72 + 32 + quad * 8];
            f32x4 zz = (f32x4){0.f, 0.f, 0.f, 0.f};
            zz = __builtin_amdgcn_mfma_f32_16x16x32_bf16(aq0, kb0, zz, 0, 0, 0);
            zz = __builtin_amdgcn_mfma_f32_16x16x32_bf16(aq1, kb1, zz, 0, 0, 0);
            s[c] = zz;
        }
        __builtin_amdgcn_s_setprio(0);
        if (l16 >= 5) { s[12][0] = -1e30f; s[12][1] = -1e30f; s[12][2] = -1e30f; s[12][3] = -1e30f; }

        // softmax over 208 cols (rows = quad*4+r, cols spread over l16)
        float mx[4], lsum[4];
#pragma unroll
        for (int r = 0; r < 4; ++r) {
            float m = s[0][r];
#pragma unroll
            for (int c = 1; c < 13; ++c) m = fmaxf(m, s[c][r]);
#pragma unroll
            for (int d = 1; d < 16; d <<= 1) m = fmaxf(m, __shfl_xor(m, d));
            mx[r] = m;
            lsum[r] = 0.f;
        }
#pragma unroll
        for (int c = 0; c < 13; ++c)
#pragma unroll
            for (int r = 0; r < 4; ++r) {
                float p = __expf(s[c][r] - mx[r]);
                s[c][r] = p;
                lsum[r] += p;
            }
#pragma unroll
        for (int r = 0; r < 4; ++r)
#pragma unroll
            for (int d = 1; d < 16; d <<= 1) lsum[r] += __shfl_xor(lsum[r], d);

        f32x4 o[4];
#pragma unroll
        for (int j = 0; j < 4; ++j) o[j] = (f32x4){0.f, 0.f, 0.f, 0.f};

        // PV pass 1: P cols 0..127 (same-wave LDS round trip, no barrier)
#pragma unroll
        for (int c = 0; c < 8; ++c)
#pragma unroll
            for (int r = 0; r < 4; ++r)
                Pw[(quad * 4 + r) * 136 + c * 16 + l16] = f2bf(s[c][r]);
        __builtin_amdgcn_s_setprio(1);
#pragma unroll
        for (int kc = 0; kc < 4; ++kc) {
            int kof = kc * 32 + quad * 8;
            bf16x8 ap = *(const bf16x8*)&Pw[l16 * 136 + kof];
#pragma unroll
            for (int j = 0; j < 4; ++j) {
                bf16x8 bv = *(const bf16x8*)&Vt[(j * 16 + l16) * 216 + kof];
                o[j] = __builtin_amdgcn_mfma_f32_16x16x32_bf16(ap, bv, o[j], 0, 0, 0);
            }
        }
        __builtin_amdgcn_s_setprio(0);
        // PV pass 2: P cols 128..207 -> buffer cols 0..79; cols 80..95 zeroed (p==0)
#pragma unroll
        for (int r = 0; r < 4; ++r)
            Pw[(quad * 4 + r) * 136 + 80 + l16] = 0;
#pragma unroll
        for (int c = 8; c < 13; ++c)
#pragma unroll
            for (int r = 0; r < 4; ++r)
                Pw[(quad * 4 + r) * 136 + (c - 8) * 16 + l16] = f2bf(s[c][r]);
        __builtin_amdgcn_s_setprio(1);
#pragma unroll
        for (int kc = 0; kc < 3; ++kc) {
            int kofA = kc * 32 + quad * 8;
            // kc==2, quad>=2 -> kt 208..223 where p==0 exactly; clamp LDS read in-range
            int kofB = (kc == 2 && quad >= 2) ? 0 : kofA;
            bf16x8 ap = *(const bf16x8*)&Pw[l16 * 136 + kofA];
#pragma unroll
            for (int j = 0; j < 4; ++j) {
                bf16x8 bv = *(const bf16x8*)&Vt[(j * 16 + l16) * 216 + 128 + kofB];
                o[j] = __builtin_amdgcn_mfma_f32_16x16x32_bf16(ap, bv, o[j], 0, 0, 0);
            }
        }
        __builtin_amdgcn_s_setprio(0);

        // epilogue: divide by l, store fp32 [B, tok, 768]
        int tokbase = tile * 16 + quad * 4;
#pragma unroll
        for (int r = 0; r < 4; ++r) {
            int tr = tokbase + r;
            if (tr >= 197) continue;
            float inv = 1.f / lsum[r];
#pragma unroll
            for (int j = 0; j < 4; ++j)
                out[((size_t)(bb * 197 + tr)) * 768 + h * 64 + j * 16 + l16] = o[j][r] * inv;
        }
    }
}

extern "C" void kernel_launch(void* const* d_in, const int* in_sizes, int n_in,
                              void* d_out, int out_size, void* d_ws, size_t ws_size,
                              hipStream_t stream) {
    const float* X    = (const float*)d_in[0];   // [64,197,768]
    const float* W    = (const float*)d_in[1];   // [768,2304]
    const float* bias = (const float*)d_in[2];   // [2304]
    float* out = (float*)d_out;                  // [64,197,768]

    // Xc and Wc (chunk-order staging images) live in d_ws
    unsigned short* Xc = (unsigned short*)d_ws;
    unsigned short* Wc = (unsigned short*)d_ws + XC_ELEMS;

    prep_kernel<<<2752, 256, 0, stream>>>(X, Xc, W, Wc);
    fused_kernel<<<768, 768, 0, stream>>>(Xc, Wc, bias, out);
}